// Round 15
// baseline (109.699 us; speedup 1.0000x reference)
//
#include <hip/hip_runtime.h>
#include <math.h>

#define H    2048
#define NE   64
#define TOKB 64
#define TAU  4.0e-3f
#define NEGF (-3.0e38f)

typedef __bf16 bf16x8 __attribute__((ext_vector_type(8)));
typedef float  f32x16 __attribute__((ext_vector_type(16)));

#define MFMA(a, b, c) __builtin_amdgcn_mfma_f32_32x32x16_bf16((a), (b), (c), 0, 0, 0)
#define LD4(p) (*reinterpret_cast<const float4*>(p))

__device__ __forceinline__ void cvt8(const float4 a, const float4 b,
                                     bf16x8& hi, bf16x8& lo) {
    const float v0 = a.x, v1 = a.y, v2 = a.z, v3 = a.w;
    const float v4 = b.x, v5 = b.y, v6 = b.z, v7 = b.w;
    hi[0] = (__bf16)v0; lo[0] = (__bf16)(v0 - (float)hi[0]);
    hi[1] = (__bf16)v1; lo[1] = (__bf16)(v1 - (float)hi[1]);
    hi[2] = (__bf16)v2; lo[2] = (__bf16)(v2 - (float)hi[2]);
    hi[3] = (__bf16)v3; lo[3] = (__bf16)(v3 - (float)hi[3]);
    hi[4] = (__bf16)v4; lo[4] = (__bf16)(v4 - (float)hi[4]);
    hi[5] = (__bf16)v5; lo[5] = (__bf16)(v5 - (float)hi[5]);
    hi[6] = (__bf16)v6; lo[6] = (__bf16)(v6 - (float)hi[6]);
    hi[7] = (__bf16)v7; lo[7] = (__bf16)(v7 - (float)hi[7]);
}

__device__ __forceinline__ void gll16(const void* g, void* l) {
    __builtin_amdgcn_global_load_lds(
        (const __attribute__((address_space(1))) void*)g,
        (__attribute__((address_space(3))) void*)l, 16, 0, 0);
}

// ---- Pass 0: prepack W (fragment-coalesced, r13 layout, proven) ------------
// Wp per k-step g: 4096 B = [hi: kh0 1KB | kh1 1KB][lo: same]; within 1KB e*16B
__global__ __launch_bounds__(256) void prep_w(
    const float* __restrict__ w, __bf16* __restrict__ wp, int* __restrict__ wl)
{
    const int e   = blockIdx.x;
    const int tid = threadIdx.x;
    if (e == 0 && tid == 0) wl[0] = 0;
    const float4 a = LD4(&w[e * H + tid * 8]);
    const float4 b = LD4(&w[e * H + tid * 8 + 4]);
    bf16x8 hi, lo;
    cvt8(a, b, hi, lo);
    const int g  = tid >> 1;
    const int kh = tid & 1;
    char* base = (char*)wp + (size_t)g * 4096 + kh * 1024 + e * 16;
    *reinterpret_cast<bf16x8*>(base)        = hi;
    *reinterpret_cast<bf16x8*>(base + 2048) = lo;
}

// ---- Pass 1: coarse-burst staging. chunk = (32-token grp) x (128-k window) -
// 8 waves = 8 k-slices. W streamed LINEARLY from Wp (32KB windows, 2-ring).
// x staged 512B/row bursts (16KB chunks, 4-ring). LDS = 128 KB exactly.
__global__ __launch_bounds__(512) void moe_gate_mfma(
    const float* __restrict__ x, const __bf16* __restrict__ wp,
    float* __restrict__ out, int woff,
    int* __restrict__ wl, int wlcap)
{
    extern __shared__ char lds[];     // W ring 2x32768 @0, x ring 4x16384 @65536

    const int tid  = threadIdx.x;
    const int lane = tid & 63;
    const int kq   = tid >> 6;        // wave = k-slice 0..7
    const int lo5  = lane & 31;
    const int hi5  = lane >> 5;
    const int t0   = blockIdx.x * TOKB;

    char* Xr = lds + 65536;

    // staging units: this thread handles u0,u1 (1024 16B-units per 16KB slab)
    const int u0 = (kq * 2 + 0) * 64 + lane;
    const int u1 = (kq * 2 + 1) * 64 + lane;
    const char* xb  = (const char*)x;
    const char* wpb = (const char*)wp;
    // x src byte offsets (row = u>>5, slot = u&31, swizzle slot^row), grp0 win0
    const size_t xo0 = (size_t)(t0 + (u0 >> 5)) * 8192 + (((u0 & 31) ^ (u0 >> 5)) << 4);
    const size_t xo1 = (size_t)(t0 + (u1 >> 5)) * 8192 + (((u1 & 31) ^ (u1 >> 5)) << 4);
    // grp1 adds 32 rows = 256 KB; window w adds w*512 B

    f32x16 a00, a10, a01, a11;        // acc[etile][grp]
    #pragma unroll
    for (int i = 0; i < 16; ++i) { a00[i]=0.f; a10[i]=0.f; a01[i]=0.f; a11[i]=0.f; }

    // prologue: W(0) h0,h1 ; x(0) grp0w0 ; x(1) grp1w0 ; x(2) grp0w1  (10 ops)
    gll16(wpb +         u0*16, lds +         u0*16);
    gll16(wpb +         u1*16, lds +         u1*16);
    gll16(wpb + 16384 + u0*16, lds + 16384 + u0*16);
    gll16(wpb + 16384 + u1*16, lds + 16384 + u1*16);
    gll16(xb + xo0,            Xr + 0*16384 + u0*16);
    gll16(xb + xo1,            Xr + 0*16384 + u1*16);
    gll16(xb + xo0 + 262144,   Xr + 1*16384 + u0*16);
    gll16(xb + xo1 + 262144,   Xr + 1*16384 + u1*16);
    gll16(xb + xo0 + 512,      Xr + 2*16384 + u0*16);
    gll16(xb + xo1 + 512,      Xr + 2*16384 + u1*16);

    // read-side offsets
    const int s0  = kq * 4 + hi5 * 2;              // x slot (32/row)
    const int xr0 = lo5 * 512 + (((s0)     ^ lo5) << 4);
    const int xr1 = lo5 * 512 + (((s0 + 1) ^ lo5) << 4);
    const int wfA = kq * 4096 + hi5 * 1024 + lo5 * 16;  // +part*2048 +et*512

    for (int win = 0; win < 16; ++win) {
        const int rA = (2 * win) & 3;              // x ring: chunk 2w
        const int rB = (rA + 1) & 3;               // chunk 2w+1
        const int wS = (rA + 3) & 3;               // dst for x(2w+3)
        const char* wb = lds + (win & 1) * 32768;  // computed, no pointer array

        // ======== chunk A: grp 0 ========
        if (win < 15) { asm volatile("s_waitcnt vmcnt(4)" ::: "memory"); }
        else          { asm volatile("s_waitcnt vmcnt(2)" ::: "memory"); }
        __builtin_amdgcn_s_barrier();
        if (win < 15) {                            // W(win+1) both halves; x(2w+3) grp1
            const size_t wno = (size_t)(win + 1) * 32768;
            char* wd = lds + ((win + 1) & 1) * 32768;
            gll16(wpb + wno +         u0*16, wd +         u0*16);
            gll16(wpb + wno +         u1*16, wd +         u1*16);
            gll16(wpb + wno + 16384 + u0*16, wd + 16384 + u0*16);
            gll16(wpb + wno + 16384 + u1*16, wd + 16384 + u1*16);
            const size_t xoff = 262144 + (size_t)(win + 1) * 512;
            gll16(xb + xo0 + xoff, Xr + wS*16384 + u0*16);
            gll16(xb + xo1 + xoff, Xr + wS*16384 + u1*16);
        }
        {
            const char* xbuf = Xr + rA * 16384;
            const bf16x8 ah0 = *reinterpret_cast<const bf16x8*>(wb + wfA);
            const bf16x8 al0 = *reinterpret_cast<const bf16x8*>(wb + wfA + 2048);
            const bf16x8 ah1 = *reinterpret_cast<const bf16x8*>(wb + wfA + 512);
            const bf16x8 al1 = *reinterpret_cast<const bf16x8*>(wb + wfA + 2560);
            const float4 b1  = *reinterpret_cast<const float4*>(xbuf + xr0);
            const float4 b2  = *reinterpret_cast<const float4*>(xbuf + xr1);
            bf16x8 bh, bl;
            cvt8(b1, b2, bh, bl);
            a00 = MFMA(ah0, bh, a00);  a10 = MFMA(ah1, bh, a10);
            a00 = MFMA(ah0, bl, a00);  a10 = MFMA(ah1, bl, a10);
            a00 = MFMA(al0, bh, a00);  a10 = MFMA(al1, bh, a10);
        }

        // ======== chunk B: grp 1 ========
        if (win < 15) { asm volatile("s_waitcnt vmcnt(8)" ::: "memory"); }
        else          { asm volatile("s_waitcnt vmcnt(0)" ::: "memory"); }
        __builtin_amdgcn_s_barrier();
        if (win < 14) {                            // x(2w+4) grp0, window w+2
            const size_t xoff = (size_t)(win + 2) * 512;
            gll16(xb + xo0 + xoff, Xr + rA*16384 + u0*16);
            gll16(xb + xo1 + xoff, Xr + rA*16384 + u1*16);
        }
        {
            const char* xbuf = Xr + rB * 16384;
            const bf16x8 ah0 = *reinterpret_cast<const bf16x8*>(wb + wfA);
            const bf16x8 al0 = *reinterpret_cast<const bf16x8*>(wb + wfA + 2048);
            const bf16x8 ah1 = *reinterpret_cast<const bf16x8*>(wb + wfA + 512);
            const bf16x8 al1 = *reinterpret_cast<const bf16x8*>(wb + wfA + 2560);
            const float4 b1  = *reinterpret_cast<const float4*>(xbuf + xr0);
            const float4 b2  = *reinterpret_cast<const float4*>(xbuf + xr1);
            bf16x8 bh, bl;
            cvt8(b1, b2, bh, bl);
            a01 = MFMA(ah0, bh, a01);  a11 = MFMA(ah1, bh, a11);
            a01 = MFMA(ah0, bl, a01);  a11 = MFMA(ah1, bl, a11);
            a01 = MFMA(al0, bh, a01);  a11 = MFMA(al1, bh, a11);
        }
    }

    // ---- 8-way k-slice reduction: kq 1..7 write partials, kq 0 sums --------
    __syncthreads();
    float* S = reinterpret_cast<float*>(lds);      // 7*64*65*4 = 116480 B
    if (kq != 0) {
        #pragma unroll
        for (int r = 0; r < 16; ++r) {
            const int e0 = (r & 3) + 8 * (r >> 2) + 4 * hi5;
            const int b0 = ((kq - 1) * 64 +      lo5) * 65;
            const int b1 = ((kq - 1) * 64 + 32 + lo5) * 65;
            S[b0 + e0]      = a00[r];
            S[b0 + 32 + e0] = a10[r];
            S[b1 + e0]      = a01[r];
            S[b1 + 32 + e0] = a11[r];
        }
    }
    __syncthreads();
    if (kq != 0) return;
    #pragma unroll
    for (int q = 1; q < 8; ++q) {
        #pragma unroll
        for (int r = 0; r < 16; ++r) {
            const int e0 = (r & 3) + 8 * (r >> 2) + 4 * hi5;
            const int b0 = ((q - 1) * 64 +      lo5) * 65;
            const int b1 = ((q - 1) * 64 + 32 + lo5) * 65;
            a00[r] += S[b0 + e0];
            a10[r] += S[b0 + 32 + e0];
            a01[r] += S[b1 + e0];
            a11[r] += S[b1 + 32 + e0];
        }
    }

    // ---- epilogue per token group (r12-verified top-3 + lane-pair merge) ----
    #pragma unroll
    for (int g = 0; g < 2; ++g) {
        const f32x16& A0 = (g == 0) ? a00 : a01;   // g is compile-time (unrolled)
        const f32x16& A1 = (g == 0) ? a10 : a11;

        float m1 = NEGF, m2 = NEGF, m3 = NEGF;
        int   i1 = 0, i2 = 0;
        #pragma unroll
        for (int r = 0; r < 16; ++r) {
            const float v = A0[r];
            const int   e = (r & 3) + 8 * (r >> 2) + 4 * hi5;
            if (v > m1)      { m3 = m2; m2 = m1; i2 = i1; m1 = v; i1 = e; }
            else if (v > m2) { m3 = m2; m2 = v; i2 = e; }
            else if (v > m3) { m3 = v; }
        }
        #pragma unroll
        for (int r = 0; r < 16; ++r) {
            const float v = A1[r];
            const int   e = 32 + (r & 3) + 8 * (r >> 2) + 4 * hi5;
            if (v > m1)      { m3 = m2; m2 = m1; i2 = i1; m1 = v; i1 = e; }
            else if (v > m2) { m3 = m2; m2 = v; i2 = e; }
            else if (v > m3) { m3 = v; }
        }

        const float n1 = __shfl_xor(m1, 32), n2 = __shfl_xor(m2, 32), n3 = __shfl_xor(m3, 32);
        const int   j1 = __shfl_xor(i1, 32), j2 = __shfl_xor(i2, 32);

        float c1, c2, c3, d1, d2, d3; int ic1, ic2, id1, id2;
        const bool aF = (m1 > n1) || (m1 == n1 && i1 < j1);
        if (aF) { c1=m1; c2=m2; c3=m3; ic1=i1; ic2=i2; d1=n1; d2=n2; d3=n3; id1=j1; id2=j2; }
        else    { c1=n1; c2=n2; c3=n3; ic1=j1; ic2=j2; d1=m1; d2=m2; d3=m3; id1=i1; id2=i2; }

        const float o1 = c1; const int oi1 = ic1;
        float o2, o3; int oi2;
        const bool c2F = (c2 > d1) || (c2 == d1 && ic2 < id1);
        if (c2F) { o2 = c2; oi2 = ic2; o3 = (c3 > d1) ? c3 : d1; }
        else     { o2 = d1; oi2 = id1; o3 = (c2 > d2) ? c2 : d2; }

        if (hi5 == 0) {
            const int t = t0 + g * 32 + lo5;
            const float r = expf(o2 - o1);
            const float s = 1.0f + r;
            out[2 * t + 0]        = (float)oi1;
            out[2 * t + 1]        = (float)oi2;
            out[woff + 2 * t + 0] = 1.0f / s;
            out[woff + 2 * t + 1] = r / s;
            if ((o1 - o2 < TAU) || (o2 - o3 < TAU)) {
                const int pos = atomicAdd(wl, 1);
                if (pos < wlcap) wl[1 + pos] = t;
            }
        }
    }
}

// ---- Pass 2: fp64 refine (unchanged, proven) -------------------------------
__global__ __launch_bounds__(256) void moe_refine_fp64(
    const float* __restrict__ x, const float* __restrict__ w,
    float* __restrict__ out, int woff,
    const int* __restrict__ wl, int wlcap)
{
    __shared__ double Sd[3][NE];
    const int lane = threadIdx.x & 63;
    const int wv   = threadIdx.x >> 6;
    const int ks   = wv * 512;
    int cnt = wl[0];
    if (cnt > wlcap) cnt = wlcap;

    for (int i = blockIdx.x; i < cnt; i += gridDim.x) {
        const int t = wl[1 + i];

        const float4 xa = LD4(&x[(size_t)t * H + ks + lane * 4]);
        const float4 xb = LD4(&x[(size_t)t * H + ks + 256 + lane * 4]);
        const double x0 = xa.x, x1 = xa.y, x2 = xa.z, x3 = xa.w;
        const double x4 = xb.x, x5 = xb.y, x6 = xb.z, x7 = xb.w;

        double myacc = 0.0;
        #pragma unroll 4
        for (int e = 0; e < NE; ++e) {
            const float4 wa = LD4(&w[(size_t)e * H + ks + lane * 4]);
            const float4 wb = LD4(&w[(size_t)e * H + ks + 256 + lane * 4]);
            double sA = 0.0, sB = 0.0;
            sA = fma((double)wa.x, x0, sA); sA = fma((double)wa.y, x1, sA);
            sA = fma((double)wa.z, x2, sA); sA = fma((double)wa.w, x3, sA);
            sB = fma((double)wb.x, x4, sB); sB = fma((double)wb.y, x5, sB);
            sB = fma((double)wb.z, x6, sB); sB = fma((double)wb.w, x7, sB);
            double s = sA + sB;
            #pragma unroll
            for (int off = 1; off < 64; off <<= 1)
                s += __shfl_xor(s, off);
            if (lane == e) myacc = s;
        }

        if (wv > 0) Sd[wv - 1][lane] = myacc;
        __syncthreads();
        if (wv == 0) {
            const double acc = ((myacc + Sd[0][lane]) + Sd[1][lane]) + Sd[2][lane];

            double v = acc; int bi = lane;
            #pragma unroll
            for (int off = 32; off > 0; off >>= 1) {
                double ov = __shfl_xor(v, off);
                int    oi = __shfl_xor(bi, off);
                if (ov > v || (ov == v && oi < bi)) { v = ov; bi = oi; }
            }
            const double m1 = v; const int i1 = bi;

            double v2 = (lane == i1) ? -1.0e300 : acc; int b2 = lane;
            #pragma unroll
            for (int off = 32; off > 0; off >>= 1) {
                double ov = __shfl_xor(v2, off);
                int    oi = __shfl_xor(b2, off);
                if (ov > v2 || (ov == v2 && oi < b2)) { v2 = ov; b2 = oi; }
            }
            const double m2 = v2; const int i2 = b2;

            if (lane == 0) {
                const double r = exp(m2 - m1);
                const double s = 1.0 + r;
                out[2 * t + 0]        = (float)i1;
                out[2 * t + 1]        = (float)i2;
                out[woff + 2 * t + 0] = (float)(1.0 / s);
                out[woff + 2 * t + 1] = (float)(r / s);
            }
        }
        __syncthreads();
    }
}

extern "C" void kernel_launch(void* const* d_in, const int* in_sizes, int n_in,
                              void* d_out, int out_size, void* d_ws, size_t ws_size,
                              hipStream_t stream) {
    const float* x   = (const float*)d_in[0];
    const float* wgt = (const float*)d_in[1];
    float* out = (float*)d_out;

    const int T    = in_sizes[0] / H;   // 16384
    const int woff = out_size / 2;      // 32768

    int*    wl = (int*)d_ws;
    __bf16* wp = (__bf16*)((char*)d_ws + 131072);   // 512 KB prepacked W
    int wlcap = T;

    (void)hipFuncSetAttribute((const void*)moe_gate_mfma,
                              hipFuncAttributeMaxDynamicSharedMemorySize, 131072);

    prep_w<<<dim3(NE), dim3(256), 0, stream>>>(wgt, wp, wl);

    moe_gate_mfma<<<dim3(T / TOKB), dim3(512), 131072, stream>>>(
        x, wp, out, woff, wl, wlcap);

    moe_refine_fp64<<<dim3(512), dim3(256), 0, stream>>>(
        x, wgt, out, woff, wl, wlcap);
}

// Round 16
// 81.914 us; speedup vs baseline: 1.3392x; 1.3392x over previous
//
#include <hip/hip_runtime.h>
#include <math.h>

#define H    2048
#define NE   64
#define TOKB 32
#define KC   128
#define NCH  16           // H / KC
#define TAU  4.0e-3f
#define NEGF (-3.0e38f)

typedef __bf16 bf16x8 __attribute__((ext_vector_type(8)));
typedef float  f32x16 __attribute__((ext_vector_type(16)));

#define MFMA(a, b, c) __builtin_amdgcn_mfma_f32_32x32x16_bf16((a), (b), (c), 0, 0, 0)
#define LD4(p) (*reinterpret_cast<const float4*>(p))

__device__ __forceinline__ void cvt8(const float4 a, const float4 b,
                                     bf16x8& hi, bf16x8& lo) {
    const float v0 = a.x, v1 = a.y, v2 = a.z, v3 = a.w;
    const float v4 = b.x, v5 = b.y, v6 = b.z, v7 = b.w;
    hi[0] = (__bf16)v0; lo[0] = (__bf16)(v0 - (float)hi[0]);
    hi[1] = (__bf16)v1; lo[1] = (__bf16)(v1 - (float)hi[1]);
    hi[2] = (__bf16)v2; lo[2] = (__bf16)(v2 - (float)hi[2]);
    hi[3] = (__bf16)v3; lo[3] = (__bf16)(v3 - (float)hi[3]);
    hi[4] = (__bf16)v4; lo[4] = (__bf16)(v4 - (float)hi[4]);
    hi[5] = (__bf16)v5; lo[5] = (__bf16)(v5 - (float)hi[5]);
    hi[6] = (__bf16)v6; lo[6] = (__bf16)(v6 - (float)hi[6]);
    hi[7] = (__bf16)v7; lo[7] = (__bf16)(v7 - (float)hi[7]);
}

__device__ __forceinline__ void gll16(const void* g, void* l) {
    __builtin_amdgcn_global_load_lds(
        (const __attribute__((address_space(1))) void*)g,
        (__attribute__((address_space(3))) void*)l, 16, 0, 0);
}

// ---- Pass 0: prepack W (fragment-coalesced, r13/r15-proven layout) ---------
// Wp per k-step g (16 k): 4096 B = [hi: kh0 1KB | kh1 1KB][lo: same]; e*16B in 1KB
__global__ __launch_bounds__(256) void prep_w(
    const float* __restrict__ w, __bf16* __restrict__ wp, int* __restrict__ wl)
{
    const int e   = blockIdx.x;
    const int tid = threadIdx.x;
    if (e == 0 && tid == 0) wl[0] = 0;
    const float4 a = LD4(&w[e * H + tid * 8]);
    const float4 b = LD4(&w[e * H + tid * 8 + 4]);
    bf16x8 hi, lo;
    cvt8(a, b, hi, lo);
    const int g  = tid >> 1;
    const int kh = tid & 1;
    char* base = (char*)wp + (size_t)g * 4096 + kh * 1024 + e * 16;
    *reinterpret_cast<bf16x8*>(base)        = hi;
    *reinterpret_cast<bf16x8*>(base + 2048) = lo;
}

// ---- Pass 1: x-only LDS ring; A from L2 into regs, issued FIRST ------------
// 512 thr / 8 waves = 8 k-slices (1 k-step each); 32 tokens x 64 experts.
// x ring: 4 x 16 KB (32 rows x 512 B, slot16 ^= row). Grid 512 = 2 blocks/CU.
__global__ __launch_bounds__(512) void moe_gate_mfma(
    const float* __restrict__ x, const __bf16* __restrict__ wp,
    float* __restrict__ out, int woff,
    int* __restrict__ wl, int wlcap)
{
    extern __shared__ char lds[];     // 65536 B

    const int tid  = threadIdx.x;
    const int lane = tid & 63;
    const int kq   = tid >> 6;        // k-slice 0..7 (16 k each per 128-k chunk)
    const int lo5  = lane & 31;
    const int hi5  = lane >> 5;
    const int t0   = blockIdx.x * TOKB;

    // ---- x staging: 2 x 16B units per thread, pre-swizzled source ----------
    const char* xb = (const char*)x;
    const int u0 = tid, u1 = 512 + tid;            // unit ids 0..1023
    const int r0 = u0 >> 5, r1 = u1 >> 5;          // token rows
    const size_t xs0 = (size_t)(t0 + r0) * 8192 + (((u0 & 31) ^ r0) << 4);
    const size_t xs1 = (size_t)(t0 + r1) * 8192 + (((u1 & 31) ^ (r1 & 31)) << 4);
    const int ld0 = u0 * 16, ld1 = u1 * 16;        // LDS offsets within slab

    // ---- A source: lane's fragment slot in Wp k-step group -----------------
    const char* wpA = (const char*)wp + kq * 4096 + hi5 * 1024 + lo5 * 16;

    // ---- x read-side swizzled offsets --------------------------------------
    const int s0 = kq * 4 + hi5 * 2;               // 16B slot of this lane's k
    const int offB0 = lo5 * 512 + (((s0)     ^ lo5) << 4);
    const int offB1 = lo5 * 512 + (((s0 + 1) ^ lo5) << 4);

    f32x16 acc0, acc1;
    #pragma unroll
    for (int i = 0; i < 16; ++i) { acc0[i] = 0.f; acc1[i] = 0.f; }

    bf16x8 A[2][4];                                // [parity][ah0,ah1,al0,al1]

    // prologue: A(0) regs first, then x chunks 0,1,2
    A[0][0] = *reinterpret_cast<const bf16x8*>(wpA);
    A[0][1] = *reinterpret_cast<const bf16x8*>(wpA + 512);
    A[0][2] = *reinterpret_cast<const bf16x8*>(wpA + 2048);
    A[0][3] = *reinterpret_cast<const bf16x8*>(wpA + 2560);
    __builtin_amdgcn_sched_barrier(0);
    gll16(xb + xs0,        lds + 0 * 16384 + ld0);
    gll16(xb + xs1,        lds + 0 * 16384 + ld1);
    gll16(xb + xs0 + 512,  lds + 1 * 16384 + ld0);
    gll16(xb + xs1 + 512,  lds + 1 * 16384 + ld1);
    gll16(xb + xs0 + 1024, lds + 2 * 16384 + ld0);
    gll16(xb + xs1 + 1024, lds + 2 * 16384 + ld1);
    __builtin_amdgcn_sched_barrier(0);

    #pragma unroll
    for (int c = 0; c < NCH; ++c) {
        // wait: A(c) regs + own x(c) staged (audited issue-order schedule)
        if (c == 0)       { asm volatile("s_waitcnt vmcnt(4)" ::: "memory"); }
        else if (c <= 13) { asm volatile("s_waitcnt vmcnt(2)" ::: "memory"); }
        else              { asm volatile("s_waitcnt vmcnt(0)" ::: "memory"); }
        __builtin_amdgcn_s_barrier();

        // 1) A(c+1) register loads FIRST (in-order vmcnt: their wait only
        //    forces x-loads that are already due)
        if (c + 1 < NCH) {
            const char* wc = wpA + (size_t)(c + 1) * 32768;
            A[(c + 1) & 1][0] = *reinterpret_cast<const bf16x8*>(wc);
            A[(c + 1) & 1][1] = *reinterpret_cast<const bf16x8*>(wc + 512);
            A[(c + 1) & 1][2] = *reinterpret_cast<const bf16x8*>(wc + 2048);
            A[(c + 1) & 1][3] = *reinterpret_cast<const bf16x8*>(wc + 2560);
        }
        __builtin_amdgcn_sched_barrier(0);
        // 2) x(c+3) gll16 prefetch
        if (c + 3 < NCH) {
            gll16(xb + xs0 + (size_t)(c + 3) * 512,
                  lds + ((c + 3) & 3) * 16384 + ld0);
            gll16(xb + xs1 + (size_t)(c + 3) * 512,
                  lds + ((c + 3) & 3) * 16384 + ld1);
        }
        __builtin_amdgcn_sched_barrier(0);

        // 3) compute chunk c
        const char* xbuf = lds + (c & 3) * 16384;
        const float4 b1 = *reinterpret_cast<const float4*>(xbuf + offB0);
        const float4 b2 = *reinterpret_cast<const float4*>(xbuf + offB1);
        bf16x8 bh, bl;
        cvt8(b1, b2, bh, bl);
        acc0 = MFMA(A[c & 1][0], bh, acc0);   // hi*hi
        acc1 = MFMA(A[c & 1][1], bh, acc1);
        acc0 = MFMA(A[c & 1][0], bl, acc0);   // hi*lo
        acc1 = MFMA(A[c & 1][1], bl, acc1);
        acc0 = MFMA(A[c & 1][2], bh, acc0);   // lo*hi
        acc1 = MFMA(A[c & 1][3], bh, acc1);
    }

    // ---- 8-way k-slice reduction: kq 1..7 write, kq 0 sums -----------------
    __syncthreads();
    float* S = reinterpret_cast<float*>(lds);      // 7*32*65*4 = 58240 < 65536
    if (kq != 0) {
        const int base = ((kq - 1) * 32 + lo5) * 65;
        #pragma unroll
        for (int r = 0; r < 16; ++r) {
            const int e0 = (r & 3) + 8 * (r >> 2) + 4 * hi5;
            S[base + e0]      = acc0[r];
            S[base + 32 + e0] = acc1[r];
        }
    }
    __syncthreads();
    if (kq != 0) return;
    #pragma unroll
    for (int q = 1; q < 8; ++q) {
        const int base = ((q - 1) * 32 + lo5) * 65;
        #pragma unroll
        for (int r = 0; r < 16; ++r) {
            const int e0 = (r & 3) + 8 * (r >> 2) + 4 * hi5;
            acc0[r] += S[base + e0];
            acc1[r] += S[base + 32 + e0];
        }
    }

    // ---- per-lane top-3 (e ascending => stable), lane-pair merge -----------
    float m1 = NEGF, m2 = NEGF, m3 = NEGF;
    int   i1 = 0, i2 = 0;
    #pragma unroll
    for (int r = 0; r < 16; ++r) {
        const float v = acc0[r];
        const int   e = (r & 3) + 8 * (r >> 2) + 4 * hi5;
        if (v > m1)      { m3 = m2; m2 = m1; i2 = i1; m1 = v; i1 = e; }
        else if (v > m2) { m3 = m2; m2 = v; i2 = e; }
        else if (v > m3) { m3 = v; }
    }
    #pragma unroll
    for (int r = 0; r < 16; ++r) {
        const float v = acc1[r];
        const int   e = 32 + (r & 3) + 8 * (r >> 2) + 4 * hi5;
        if (v > m1)      { m3 = m2; m2 = m1; i2 = i1; m1 = v; i1 = e; }
        else if (v > m2) { m3 = m2; m2 = v; i2 = e; }
        else if (v > m3) { m3 = v; }
    }

    const float n1 = __shfl_xor(m1, 32), n2 = __shfl_xor(m2, 32), n3 = __shfl_xor(m3, 32);
    const int   j1 = __shfl_xor(i1, 32), j2 = __shfl_xor(i2, 32);

    float a1, a2, a3, b1, b2, b3; int ia1, ia2, ib1, ib2;
    const bool aF = (m1 > n1) || (m1 == n1 && i1 < j1);
    if (aF) { a1=m1; a2=m2; a3=m3; ia1=i1; ia2=i2; b1=n1; b2=n2; b3=n3; ib1=j1; ib2=j2; }
    else    { a1=n1; a2=n2; a3=n3; ia1=j1; ia2=j2; b1=m1; b2=m2; b3=m3; ib1=i1; ib2=i2; }

    const float o1 = a1; const int oi1 = ia1;
    float o2, o3; int oi2;
    const bool a2F = (a2 > b1) || (a2 == b1 && ia2 < ib1);
    if (a2F) { o2 = a2; oi2 = ia2; o3 = (a3 > b1) ? a3 : b1; }
    else     { o2 = b1; oi2 = ib1; o3 = (a2 > b2) ? a2 : b2; }

    if (hi5 == 0) {
        const int t = t0 + lo5;
        const float r = expf(o2 - o1);
        const float s = 1.0f + r;
        out[2 * t + 0]        = (float)oi1;
        out[2 * t + 1]        = (float)oi2;
        out[woff + 2 * t + 0] = 1.0f / s;
        out[woff + 2 * t + 1] = r / s;
        if ((o1 - o2 < TAU) || (o2 - o3 < TAU)) {
            const int pos = atomicAdd(wl, 1);
            if (pos < wlcap) wl[1 + pos] = t;
        }
    }
}

// ---- Pass 2: fp64 refine (unchanged, proven) -------------------------------
__global__ __launch_bounds__(256) void moe_refine_fp64(
    const float* __restrict__ x, const float* __restrict__ w,
    float* __restrict__ out, int woff,
    const int* __restrict__ wl, int wlcap)
{
    __shared__ double Sd[3][NE];
    const int lane = threadIdx.x & 63;
    const int wv   = threadIdx.x >> 6;
    const int ks   = wv * 512;
    int cnt = wl[0];
    if (cnt > wlcap) cnt = wlcap;

    for (int i = blockIdx.x; i < cnt; i += gridDim.x) {
        const int t = wl[1 + i];

        const float4 xa = LD4(&x[(size_t)t * H + ks + lane * 4]);
        const float4 xb = LD4(&x[(size_t)t * H + ks + 256 + lane * 4]);
        const double x0 = xa.x, x1 = xa.y, x2 = xa.z, x3 = xa.w;
        const double x4 = xb.x, x5 = xb.y, x6 = xb.z, x7 = xb.w;

        double myacc = 0.0;
        #pragma unroll 4
        for (int e = 0; e < NE; ++e) {
            const float4 wa = LD4(&w[(size_t)e * H + ks + lane * 4]);
            const float4 wb = LD4(&w[(size_t)e * H + ks + 256 + lane * 4]);
            double sA = 0.0, sB = 0.0;
            sA = fma((double)wa.x, x0, sA); sA = fma((double)wa.y, x1, sA);
            sA = fma((double)wa.z, x2, sA); sA = fma((double)wa.w, x3, sA);
            sB = fma((double)wb.x, x4, sB); sB = fma((double)wb.y, x5, sB);
            sB = fma((double)wb.z, x6, sB); sB = fma((double)wb.w, x7, sB);
            double s = sA + sB;
            #pragma unroll
            for (int off = 1; off < 64; off <<= 1)
                s += __shfl_xor(s, off);
            if (lane == e) myacc = s;
        }

        if (wv > 0) Sd[wv - 1][lane] = myacc;
        __syncthreads();
        if (wv == 0) {
            const double acc = ((myacc + Sd[0][lane]) + Sd[1][lane]) + Sd[2][lane];

            double v = acc; int bi = lane;
            #pragma unroll
            for (int off = 32; off > 0; off >>= 1) {
                double ov = __shfl_xor(v, off);
                int    oi = __shfl_xor(bi, off);
                if (ov > v || (ov == v && oi < bi)) { v = ov; bi = oi; }
            }
            const double m1 = v; const int i1 = bi;

            double v2 = (lane == i1) ? -1.0e300 : acc; int b2 = lane;
            #pragma unroll
            for (int off = 32; off > 0; off >>= 1) {
                double ov = __shfl_xor(v2, off);
                int    oi = __shfl_xor(b2, off);
                if (ov > v2 || (ov == v2 && oi < b2)) { v2 = ov; b2 = oi; }
            }
            const double m2 = v2; const int i2 = b2;

            if (lane == 0) {
                const double r = exp(m2 - m1);
                const double s = 1.0 + r;
                out[2 * t + 0]        = (float)i1;
                out[2 * t + 1]        = (float)i2;
                out[woff + 2 * t + 0] = (float)(1.0 / s);
                out[woff + 2 * t + 1] = (float)(r / s);
            }
        }
        __syncthreads();
    }
}

extern "C" void kernel_launch(void* const* d_in, const int* in_sizes, int n_in,
                              void* d_out, int out_size, void* d_ws, size_t ws_size,
                              hipStream_t stream) {
    const float* x   = (const float*)d_in[0];
    const float* wgt = (const float*)d_in[1];
    float* out = (float*)d_out;

    const int T    = in_sizes[0] / H;   // 16384
    const int woff = out_size / 2;      // 32768

    int*    wl = (int*)d_ws;
    __bf16* wp = (__bf16*)((char*)d_ws + 131072);   // 512 KB prepacked W
    int wlcap = T;

    (void)hipFuncSetAttribute((const void*)moe_gate_mfma,
                              hipFuncAttributeMaxDynamicSharedMemorySize, 65536);

    prep_w<<<dim3(NE), dim3(256), 0, stream>>>(wgt, wp, wl);

    moe_gate_mfma<<<dim3(T / TOKB), dim3(512), 65536, stream>>>(
        x, wp, out, woff, wl, wlcap);

    moe_refine_fp64<<<dim3(512), dim3(256), 0, stream>>>(
        x, wgt, out, woff, wl, wlcap);
}

// Round 17
// 74.377 us; speedup vs baseline: 1.4749x; 1.1013x over previous
//
#include <hip/hip_runtime.h>
#include <math.h>

#define H     2048
#define NE    64
#define TOKB  256             // tokens per block
#define KSPL  4               // K-split across blocks
#define KC    32
#define NCHB  16              // (H/KSPL)/KC
#define CHB   40960           // chunk bytes: A 8192 + B 32768
#define TAU   4.0e-3f
#define NEGF  (-3.0e38f)

typedef __bf16 bf16x8 __attribute__((ext_vector_type(8)));
typedef float  f32x16 __attribute__((ext_vector_type(16)));

#define MFMA(a, b, c) __builtin_amdgcn_mfma_f32_32x32x16_bf16((a), (b), (c), 0, 0, 0)
#define LD4(p) (*reinterpret_cast<const float4*>(p))

__device__ __forceinline__ void cvt8(const float4 a, const float4 b,
                                     bf16x8& hi, bf16x8& lo) {
    const float v0 = a.x, v1 = a.y, v2 = a.z, v3 = a.w;
    const float v4 = b.x, v5 = b.y, v6 = b.z, v7 = b.w;
    hi[0] = (__bf16)v0; lo[0] = (__bf16)(v0 - (float)hi[0]);
    hi[1] = (__bf16)v1; lo[1] = (__bf16)(v1 - (float)hi[1]);
    hi[2] = (__bf16)v2; lo[2] = (__bf16)(v2 - (float)hi[2]);
    hi[3] = (__bf16)v3; lo[3] = (__bf16)(v3 - (float)hi[3]);
    hi[4] = (__bf16)v4; lo[4] = (__bf16)(v4 - (float)hi[4]);
    hi[5] = (__bf16)v5; lo[5] = (__bf16)(v5 - (float)hi[5]);
    hi[6] = (__bf16)v6; lo[6] = (__bf16)(v6 - (float)hi[6]);
    hi[7] = (__bf16)v7; lo[7] = (__bf16)(v7 - (float)hi[7]);
}

__device__ __forceinline__ void gll16(const void* g, void* l) {
    __builtin_amdgcn_global_load_lds(
        (const __attribute__((address_space(1))) void*)g,
        (__attribute__((address_space(3))) void*)l, 16, 0, 0);
}

// ---- Pass 0: prepack W (fragment-coalesced, proven layout); zero wl --------
// Wp per k-step g (16 k): 4096 B = [hi: kh0 1KB | kh1 1KB][lo: kh0 | kh1]; e*16B
__global__ __launch_bounds__(256) void prep_w(
    const float* __restrict__ w, __bf16* __restrict__ wp, int* __restrict__ wl)
{
    const int e   = blockIdx.x;
    const int tid = threadIdx.x;
    if (e == 0 && tid == 0) wl[0] = 0;
    const float4 a = LD4(&w[e * H + tid * 8]);
    const float4 b = LD4(&w[e * H + tid * 8 + 4]);
    bf16x8 hi, lo;
    cvt8(a, b, hi, lo);
    const int g  = tid >> 1;
    const int kh = tid & 1;
    char* base = (char*)wp + (size_t)g * 4096 + kh * 1024 + e * 16;
    *reinterpret_cast<bf16x8*>(base)        = hi;
    *reinterpret_cast<bf16x8*>(base + 2048) = lo;
}

// ---- Pass 1: partial-GEMM. block = (256-token grp) x (K-quarter 512) -------
// 8 waves = 8 token-octants (32 rows x 64 experts each); NO in-block reduction.
// r12 engine: all-gll16, NBUF=3 x 40KB ring, counted vmcnt(5), dist-2.
__global__ __launch_bounds__(512) void moe_gate_mfma(
    const float* __restrict__ x, const __bf16* __restrict__ wp,
    float* __restrict__ P)          // P[bx][256 tok][64 e] fp32 partials
{
    extern __shared__ char lds[];   // 3 * 40960 = 122880 B

    const int tid  = threadIdx.x;
    const int lane = tid & 63;
    const int tq   = tid >> 6;      // wave = token octant 0..7
    const int lo5  = lane & 31;
    const int hi5  = lane >> 5;
    const int bx   = blockIdx.x;    // tg*4 + kqb
    const int tg   = bx >> 2;
    const int kqb  = bx & 3;
    const int t0   = tg * TOKB;

    // ---- staging: 5 x 16B units / thread. A linear; B swizzled-source ------
    const char* sb[5]; int sstr[5]; int sld[5];
    #pragma unroll
    for (int s = 0; s < 5; ++s) {
        const int u = s * 512 + tid;                 // 0..2559
        sld[s] = u * 16;                             // LDS offset (linear)
        if (u < 512) {                               // A: Wp, 2 k-steps/chunk
            sb[s]   = (const char*)wp + (size_t)kqb * 131072 + u * 16;
            sstr[s] = 8192;                          // chunk walk
        } else {                                     // B: x rows
            const int up  = u - 512;
            const int row = up >> 3;                 // 0..255
            const int sl  = up & 7;
            sb[s]   = (const char*)x + (size_t)(t0 + row) * 8192
                      + kqb * 2048 + ((sl ^ (row & 7)) << 4);
            sstr[s] = 128;
        }
    }

    f32x16 acc0, acc1;
    #pragma unroll
    for (int i = 0; i < 16; ++i) { acc0[i] = 0.f; acc1[i] = 0.f; }

    // prologue: chunks 0,1 (10 loads/thread outstanding)
    #pragma unroll
    for (int s = 0; s < 5; ++s) gll16(sb[s],           lds + 0 * CHB + sld[s]);
    #pragma unroll
    for (int s = 0; s < 5; ++s) gll16(sb[s] + sstr[s], lds + 1 * CHB + sld[s]);

    // ---- read-side offsets --------------------------------------------------
    const int rowB = tq * 32 + lo5;                  // this lane's token row
    const int rk   = rowB & 7;
    const int bb   = 8192 + rowB * 128;
    const int b00 = bb + (((0 + hi5 * 2)     ^ rk) << 4);   // kstep0
    const int b01 = bb + (((0 + hi5 * 2 + 1) ^ rk) << 4);
    const int b10 = bb + (((4 + hi5 * 2)     ^ rk) << 4);   // kstep1
    const int b11 = bb + (((4 + hi5 * 2 + 1) ^ rk) << 4);
    const int af  = hi5 * 1024 + lo5 * 16;           // A frag: +u*4096 +et*512 (+2048 lo)

    int ib = 0, iw = 2;
    for (int c = 0; c < NCHB; ++c) {
        if (c < NCHB - 1) { asm volatile("s_waitcnt vmcnt(5)" ::: "memory"); }
        else              { asm volatile("s_waitcnt vmcnt(0)" ::: "memory"); }
        __builtin_amdgcn_s_barrier();

        if (c + 2 < NCHB) {          // issue chunk c+2 (stays in flight)
            #pragma unroll
            for (int s = 0; s < 5; ++s)
                gll16(sb[s] + (size_t)(c + 2) * sstr[s], lds + iw * CHB + sld[s]);
        }

        const char* buf = lds + ib * CHB;
        // ---- kstep 0 ----
        {
            const bf16x8 ah0 = *reinterpret_cast<const bf16x8*>(buf + af);
            const bf16x8 ah1 = *reinterpret_cast<const bf16x8*>(buf + af + 512);
            const bf16x8 al0 = *reinterpret_cast<const bf16x8*>(buf + af + 2048);
            const bf16x8 al1 = *reinterpret_cast<const bf16x8*>(buf + af + 2560);
            const float4 v1  = LD4(buf + b00);
            const float4 v2  = LD4(buf + b01);
            bf16x8 bh, bl;
            cvt8(v1, v2, bh, bl);
            acc0 = MFMA(ah0, bh, acc0);  acc1 = MFMA(ah1, bh, acc1);
            acc0 = MFMA(ah0, bl, acc0);  acc1 = MFMA(ah1, bl, acc1);
            acc0 = MFMA(al0, bh, acc0);  acc1 = MFMA(al1, bh, acc1);
        }
        // ---- kstep 1 ----
        {
            const bf16x8 ah0 = *reinterpret_cast<const bf16x8*>(buf + 4096 + af);
            const bf16x8 ah1 = *reinterpret_cast<const bf16x8*>(buf + 4096 + af + 512);
            const bf16x8 al0 = *reinterpret_cast<const bf16x8*>(buf + 4096 + af + 2048);
            const bf16x8 al1 = *reinterpret_cast<const bf16x8*>(buf + 4096 + af + 2560);
            const float4 v1  = LD4(buf + b10);
            const float4 v2  = LD4(buf + b11);
            bf16x8 bh, bl;
            cvt8(v1, v2, bh, bl);
            acc0 = MFMA(ah0, bh, acc0);  acc1 = MFMA(ah1, bh, acc1);
            acc0 = MFMA(ah0, bl, acc0);  acc1 = MFMA(ah1, bl, acc1);
            acc0 = MFMA(al0, bh, acc0);  acc1 = MFMA(al1, bh, acc1);
        }
        ib = (ib == 2) ? 0 : ib + 1;
        iw = (iw == 2) ? 0 : iw + 1;
    }

    // ---- store partials (coalesced float4; acc[r], r=4g+j -> e = 8g+4*hi5+j)
    float* Pr = P + ((size_t)bx * TOKB + rowB) * NE;
    #pragma unroll
    for (int g = 0; g < 4; ++g) {
        *reinterpret_cast<float4*>(Pr + 8 * g + 4 * hi5) =
            make_float4(acc0[4*g], acc0[4*g+1], acc0[4*g+2], acc0[4*g+3]);
        *reinterpret_cast<float4*>(Pr + 32 + 8 * g + 4 * hi5) =
            make_float4(acc1[4*g], acc1[4*g+1], acc1[4*g+2], acc1[4*g+3]);
    }
}

// ---- Pass 2: combine K-quarters, top-3, flag (1 thread / token) ------------
__global__ __launch_bounds__(256) void moe_combine(
    const float* __restrict__ P, float* __restrict__ out, int woff,
    int* __restrict__ wl, int wlcap)
{
    const int tok = blockIdx.x * 256 + threadIdx.x;   // grid 64 -> 0..16383
    const int tg  = tok >> 8;
    const int tl  = tok & 255;

    const float* p = P + (((size_t)tg * KSPL) * TOKB + tl) * NE;
    float4 s[16];
    #pragma unroll
    for (int i = 0; i < 16; ++i) s[i] = LD4(p + i * 4);
    #pragma unroll
    for (int kq = 1; kq < KSPL; ++kq) {
        const float* q = p + (size_t)kq * TOKB * NE;
        #pragma unroll
        for (int i = 0; i < 16; ++i) {
            const float4 v = LD4(q + i * 4);
            s[i].x += v.x; s[i].y += v.y; s[i].z += v.z; s[i].w += v.w;
        }
    }

    // ascending-e top-3 (strict > keeps lowest index => stable, proven r10)
    float m1 = NEGF, m2 = NEGF, m3 = NEGF;
    int   i1 = 0, i2 = 0;
    #pragma unroll
    for (int i = 0; i < 16; ++i) {
        const float vv[4] = { s[i].x, s[i].y, s[i].z, s[i].w };
        #pragma unroll
        for (int j = 0; j < 4; ++j) {
            const float v = vv[j];
            const int   e = i * 4 + j;
            if (v > m1)      { m3 = m2; m2 = m1; i2 = i1; m1 = v; i1 = e; }
            else if (v > m2) { m3 = m2; m2 = v; i2 = e; }
            else if (v > m3) { m3 = v; }
        }
    }

    const float r = expf(m2 - m1);
    const float sden = 1.0f + r;
    out[2 * tok + 0]        = (float)i1;
    out[2 * tok + 1]        = (float)i2;
    out[woff + 2 * tok + 0] = 1.0f / sden;
    out[woff + 2 * tok + 1] = r / sden;
    if ((m1 - m2 < TAU) || (m2 - m3 < TAU)) {
        const int pos = atomicAdd(wl, 1);
        if (pos < wlcap) wl[1 + pos] = tok;
    }
}

// ---- Pass 3: fp64 refine (unchanged, proven) -------------------------------
__global__ __launch_bounds__(256) void moe_refine_fp64(
    const float* __restrict__ x, const float* __restrict__ w,
    float* __restrict__ out, int woff,
    const int* __restrict__ wl, int wlcap)
{
    __shared__ double Sd[3][NE];
    const int lane = threadIdx.x & 63;
    const int wv   = threadIdx.x >> 6;
    const int ks   = wv * 512;
    int cnt = wl[0];
    if (cnt > wlcap) cnt = wlcap;

    for (int i = blockIdx.x; i < cnt; i += gridDim.x) {
        const int t = wl[1 + i];

        const float4 xa = LD4(&x[(size_t)t * H + ks + lane * 4]);
        const float4 xb = LD4(&x[(size_t)t * H + ks + 256 + lane * 4]);
        const double x0 = xa.x, x1 = xa.y, x2 = xa.z, x3 = xa.w;
        const double x4 = xb.x, x5 = xb.y, x6 = xb.z, x7 = xb.w;

        double myacc = 0.0;
        #pragma unroll 4
        for (int e = 0; e < NE; ++e) {
            const float4 wa = LD4(&w[(size_t)e * H + ks + lane * 4]);
            const float4 wb = LD4(&w[(size_t)e * H + ks + 256 + lane * 4]);
            double sA = 0.0, sB = 0.0;
            sA = fma((double)wa.x, x0, sA); sA = fma((double)wa.y, x1, sA);
            sA = fma((double)wa.z, x2, sA); sA = fma((double)wa.w, x3, sA);
            sB = fma((double)wb.x, x4, sB); sB = fma((double)wb.y, x5, sB);
            sB = fma((double)wb.z, x6, sB); sB = fma((double)wb.w, x7, sB);
            double s = sA + sB;
            #pragma unroll
            for (int off = 1; off < 64; off <<= 1)
                s += __shfl_xor(s, off);
            if (lane == e) myacc = s;
        }

        if (wv > 0) Sd[wv - 1][lane] = myacc;
        __syncthreads();
        if (wv == 0) {
            const double acc = ((myacc + Sd[0][lane]) + Sd[1][lane]) + Sd[2][lane];

            double v = acc; int bi = lane;
            #pragma unroll
            for (int off = 32; off > 0; off >>= 1) {
                double ov = __shfl_xor(v, off);
                int    oi = __shfl_xor(bi, off);
                if (ov > v || (ov == v && oi < bi)) { v = ov; bi = oi; }
            }
            const double m1 = v; const int i1 = bi;

            double v2 = (lane == i1) ? -1.0e300 : acc; int b2 = lane;
            #pragma unroll
            for (int off = 32; off > 0; off >>= 1) {
                double ov = __shfl_xor(v2, off);
                int    oi = __shfl_xor(b2, off);
                if (ov > v2 || (ov == v2 && oi < b2)) { v2 = ov; b2 = oi; }
            }
            const double m2 = v2; const int i2 = b2;

            if (lane == 0) {
                const double r = exp(m2 - m1);
                const double s = 1.0 + r;
                out[2 * t + 0]        = (float)i1;
                out[2 * t + 1]        = (float)i2;
                out[woff + 2 * t + 0] = (float)(1.0 / s);
                out[woff + 2 * t + 1] = (float)(r / s);
            }
        }
        __syncthreads();
    }
}

extern "C" void kernel_launch(void* const* d_in, const int* in_sizes, int n_in,
                              void* d_out, int out_size, void* d_ws, size_t ws_size,
                              hipStream_t stream) {
    const float* x   = (const float*)d_in[0];
    const float* wgt = (const float*)d_in[1];
    float* out = (float*)d_out;

    const int T    = in_sizes[0] / H;   // 16384
    const int woff = out_size / 2;      // 32768

    int*    wl = (int*)d_ws;                          // 128 KB region
    __bf16* wp = (__bf16*)((char*)d_ws + 131072);     // 512 KB prepacked W
    float*  P  = (float*)((char*)d_ws + 131072 + 524288);  // 16 MB partials
    int wlcap = T;

    (void)hipFuncSetAttribute((const void*)moe_gate_mfma,
                              hipFuncAttributeMaxDynamicSharedMemorySize, 122880);

    prep_w<<<dim3(NE), dim3(256), 0, stream>>>(wgt, wp, wl);

    moe_gate_mfma<<<dim3((T / TOKB) * KSPL), dim3(512), 122880, stream>>>(x, wp, P);

    moe_combine<<<dim3(T / 256), dim3(256), 0, stream>>>(P, out, woff, wl, wlcap);

    moe_refine_fp64<<<dim3(512), dim3(256), 0, stream>>>(
        x, wgt, out, woff, wl, wlcap);
}